// Round 6
// baseline (1939.088 us; speedup 1.0000x reference)
//
#include <hip/hip_runtime.h>
#include <hip/hip_bf16.h>
#include <math.h>

constexpr int kN = 10000;   // nodes
constexpr int kE = 160000;  // edges
constexpr float kSlope = 0.2f;
constexpr unsigned kMagicB = 0x0FF0C0DEu;

typedef short v8s __attribute__((ext_vector_type(8)));
typedef float f32x4 __attribute__((ext_vector_type(4)));
typedef unsigned short ushort_t;

__device__ __forceinline__ float lrelu(float x) { return x > 0.f ? x : kSlope * x; }
__device__ __forceinline__ float elu_f(float x) { return x > 0.f ? x : (__expf(x) - 1.f); }
__device__ __forceinline__ float b2f(ushort_t u) {
    return __uint_as_float(((unsigned)u) << 16);
}
__device__ __forceinline__ float bl(unsigned u) { return __uint_as_float(u << 16); }
__device__ __forceinline__ float bh(unsigned u) { return __uint_as_float(u & 0xffff0000u); }
__device__ __forceinline__ ushort_t f2b(float f) {   // RNE f32->bf16
    unsigned u = __float_as_uint(f);
    return (ushort_t)((u + 0x7FFFu + ((u >> 16) & 1u)) >> 16);
}

// --- intra-kernel producer/consumer sync (device-scope; counters pre-zeroed in K1) ---
__device__ __forceinline__ void spin_eq(int* p, int want) {
    if (threadIdx.x == 0) {
        while (atomicAdd(p, 0) != want) __builtin_amdgcn_s_sleep(8);
    }
    __syncthreads();
    __threadfence();   // acquire: make producer writes visible to all lanes
}
__device__ __forceinline__ void signal_done(int* p) {
    __threadfence();   // release: flush this block's writes
    __syncthreads();
    if (threadIdx.x == 0) atomicAdd(p, 1);
}

// ---------------- K1: dtype detection + deg/cnt/counter zeroing ----------------
// flags layout: [0] f32in [1] idx64 [2] unused [3] C_prep [4] magicB slot
//               [5] C_agg0 [6] C_agg1 [7] C_agg2
__global__ void detect_zero(const void* __restrict__ x, const void* __restrict__ dsti,
                            int* __restrict__ flags, int* __restrict__ deg) {
    if (blockIdx.x == 0) {
        __shared__ int sb[2];
        int tid = threadIdx.x;
        if (tid == 0) { sb[0] = 0; sb[1] = 0; }
        __syncthreads();
        const ushort_t* xb = (const ushort_t*)x;
        int big = 0;
        for (int i = tid; i < 4096; i += 256) {
            float v = b2f(xb[i]);
            if (!(fabsf(v) <= 1e4f)) big = 1;
        }
        const int* d32 = (const int*)dsti;
        int hi = 0;
        for (int i = tid; i < 4096; i += 256) hi |= d32[2 * i + 1];
        if (big) atomicOr(&sb[0], 1);
        if (hi)  atomicOr(&sb[1], 1);
        __syncthreads();
        if (tid == 0) {
            flags[0] = sb[0];
            flags[1] = sb[1] ? 0 : 1;
            flags[3] = 0;   // C_prep
            flags[5] = 0;   // C_agg0
            flags[6] = 0;   // C_agg1
            flags[7] = 0;   // C_agg2
        }
    } else {
        int i = (blockIdx.x - 1) * 256 + threadIdx.x;
        if (i < 2 * kN) deg[i] = 0;    // deg + cnt contiguous
    }
}

// ---------------- prep work item (same math as R5's prep_all) ----------------
struct FrontArgs {
    const void* sm[13];
    const void* W0; const void* W1; const void* W2; const void* Wm0; const void* Wm1;
    const void* X; const void* srcIn; const void* dstIn;
    float* smallb;
    ushort_t* W0T; ushort_t* W1T; ushort_t* W2T; ushort_t* PQT; ushort_t* Wm1T;
    int* nsrc; int* ndst;
    int* flags; int* deg; int* off; int* ss; int* eid; int* dpos;
    ushort_t* Fb;
    const float* al0; const float* ar0; float* el; float* er;
};
// segments: 4865 | 131072 | 262144 | 262144 | 32768 | 8192 | 320000
constexpr int kPrepTotal = 4865 + 131072 + 262144 + 262144 + 32768 + 8192 + 320000;
constexpr int kNP = (kPrepTotal + 255) / 256;     // 3990
constexpr int kFillChunks = (kE + 1023) / 1024;   // 157
constexpr int kGy = (kN + 63) / 64;               // 157
constexpr int kGa = (kN + 3) / 4;                 // 2500

__device__ void prep_item(const FrontArgs& a, int i, int f32in, int idx64) {
    auto cv = [&](const void* p, int idx) -> ushort_t {
        return f32in ? f2b(((const float*)p)[idx]) : ((const ushort_t*)p)[idx];
    };
    if (i < 4865) {   // small f32 tensors
        int seg, offi;
        if (i < 4608)      { seg = i >> 9; offi = i & 511; }
        else if (i < 4736) { seg = 9;  offi = i - 4608; }
        else if (i < 4800) { seg = 10; offi = i - 4736; }
        else if (i < 4864) { seg = 11; offi = i - 4800; }
        else               { seg = 12; offi = 0; }
        a.smallb[i] = f32in ? ((const float*)a.sm[seg])[offi]
                            : b2f(((const ushort_t*)a.sm[seg])[offi]);
        return;
    }
    i -= 4865;
    if (i < 131072) {   // W0T [512][256]
        int n = i >> 8, k = i & 255;
        a.W0T[i] = cv(a.W0, k * 512 + n);
        return;
    }
    i -= 131072;
    if (i < 262144) {   // W1T [512][512]
        int n = i >> 9, k = i & 511;
        a.W1T[i] = cv(a.W1, k * 512 + n);
        return;
    }
    i -= 262144;
    if (i < 262144) {   // W2T [512][512]
        int n = i >> 9, k = i & 511;
        a.W2T[i] = cv(a.W2, k * 512 + n);
        return;
    }
    i -= 262144;
    if (i < 32768) {    // PQT [256][128]
        int n = i >> 7, k = i & 127;
        a.PQT[i] = cv(a.Wm0, (k + ((n < 128) ? 0 : 128)) * 128 + (n & 127));
        return;
    }
    i -= 32768;
    if (i < 8192) {     // Wm1T [64][128]
        int n = i >> 7, k = i & 127;
        a.Wm1T[i] = cv(a.Wm1, k * 64 + n);
        return;
    }
    i -= 8192;
    {                   // index normalize + degree count
        const void* in = (i < kE) ? a.srcIn : a.dstIn;
        int j = (i < kE) ? i : i - kE;
        int v = idx64 ? (int)((const long long*)in)[j] : ((const int*)in)[j];
        v = ((unsigned)v < (unsigned)kN) ? v : 0;
        if (i < kE) a.nsrc[j] = v;
        else { a.ndst[j] = v; atomicAdd(&a.deg[v], 1); }
    }
}

// ---------------- MFMA GEMM body (R0-proven K-chunk-32 structure) ----------------
// A [M,K] row-major: bf16, or f32 when (f32sel && gflags[0]) -> converted in-register.
// WT [N,K] bf16 row-major. C [M,N] bf16. ELER: fused el/er (head = bx).
template <bool ELER>
__device__ void gemm_body(const void* __restrict__ A,
                          const int* __restrict__ gflags, int f32sel,
                          const ushort_t* __restrict__ WT,
                          ushort_t* __restrict__ Cout,
                          int M, int N, int K,
                          const float* __restrict__ al,
                          const float* __restrict__ ar,
                          float* __restrict__ el,
                          float* __restrict__ er,
                          int bx, int by) {
    __shared__ __align__(16) ushort_t As[4][64][8];
    __shared__ __align__(16) ushort_t Bs[4][128][8];
    __shared__ float elred[64][2][2];
    const int t = threadIdx.x;
    const int wave = t >> 6, lane = t & 63;
    const int l16 = lane & 15, q = lane >> 4;
    const int row0 = by * 64, col0 = bx * 128;
    const int wm = (wave & 1) * 32, wn = (wave >> 1) * 64;
    const int am = t >> 2, ak8 = t & 3;
    const int sw = ak8 * 4;

    const int f32a = f32sel && gflags[0];
    const size_t arow = (size_t)min(row0 + am, M - 1) * K + ak8 * 8;
    const ushort_t* aB = (const ushort_t*)A + arow;
    const float*    aF = (const float*)A + arow;
    const ushort_t* bptr0 = WT + (size_t)(col0 + am) * K + ak8 * 8;
    const ushort_t* bptr1 = bptr0 + (size_t)64 * K;

    auto loadA = [&](int k0) -> uint4 {
        if (!f32a) return *(const uint4*)(aB + k0);
        float4 f0 = *(const float4*)(aF + k0);
        float4 f1 = *(const float4*)(aF + k0 + 4);
        uint4 r;
        r.x = (unsigned)f2b(f0.x) | ((unsigned)f2b(f0.y) << 16);
        r.y = (unsigned)f2b(f0.z) | ((unsigned)f2b(f0.w) << 16);
        r.z = (unsigned)f2b(f1.x) | ((unsigned)f2b(f1.y) << 16);
        r.w = (unsigned)f2b(f1.z) | ((unsigned)f2b(f1.w) << 16);
        return r;
    };

    uint4 ga  = loadA(0);
    uint4 gb0 = *(const uint4*)bptr0;
    uint4 gb1 = *(const uint4*)bptr1;

    f32x4 acc[2][4];
#pragma unroll
    for (int mt = 0; mt < 2; ++mt)
#pragma unroll
        for (int nt = 0; nt < 4; ++nt)
#pragma unroll
            for (int r = 0; r < 4; ++r) acc[mt][nt][r] = 0.f;

    for (int k0 = 0; k0 < K; k0 += 32) {
        __syncthreads();
        *(uint4*)&As[ak8][am ^ sw][0] = ga;
        *(uint4*)&Bs[ak8][am ^ sw][0] = gb0;
        *(uint4*)&Bs[ak8][(am + 64) ^ sw][0] = gb1;
        __syncthreads();
        if (k0 + 32 < K) {
            ga  = loadA(k0 + 32);
            gb0 = *(const uint4*)(bptr0 + k0 + 32);
            gb1 = *(const uint4*)(bptr1 + k0 + 32);
        }
        v8s af[2], bf[4];
        const int qs = q * 4;
#pragma unroll
        for (int mt = 0; mt < 2; ++mt)
            af[mt] = *(const v8s*)&As[q][(wm + mt * 16 + l16) ^ qs][0];
#pragma unroll
        for (int nt = 0; nt < 4; ++nt)
            bf[nt] = *(const v8s*)&Bs[q][(wn + nt * 16 + l16) ^ qs][0];
#pragma unroll
        for (int mt = 0; mt < 2; ++mt)
#pragma unroll
            for (int nt = 0; nt < 4; ++nt)
                acc[mt][nt] = __builtin_amdgcn_mfma_f32_16x16x32_bf16(af[mt], bf[nt],
                                                                      acc[mt][nt], 0, 0, 0);
    }
#pragma unroll
    for (int mt = 0; mt < 2; ++mt)
#pragma unroll
        for (int r = 0; r < 4; ++r) {
            int row = row0 + wm + mt * 16 + q * 4 + r;
            if (row < M) {
#pragma unroll
                for (int nt = 0; nt < 4; ++nt)
                    Cout[(size_t)row * N + col0 + wn + nt * 16 + l16] = f2b(acc[mt][nt][r]);
            }
        }
    if (ELER) {
        const int head = bx;
        float alv[4], arv[4];
#pragma unroll
        for (int nt = 0; nt < 4; ++nt) {
            alv[nt] = al[head * 128 + wn + nt * 16 + l16];
            arv[nt] = ar[head * 128 + wn + nt * 16 + l16];
        }
#pragma unroll
        for (int mt = 0; mt < 2; ++mt)
#pragma unroll
            for (int r = 0; r < 4; ++r) {
                float pel = 0.f, per = 0.f;
#pragma unroll
                for (int nt = 0; nt < 4; ++nt) {
                    pel += acc[mt][nt][r] * alv[nt];
                    per += acc[mt][nt][r] * arv[nt];
                }
                pel += __shfl_xor(pel, 1); per += __shfl_xor(per, 1);
                pel += __shfl_xor(pel, 2); per += __shfl_xor(per, 2);
                pel += __shfl_xor(pel, 4); per += __shfl_xor(per, 4);
                pel += __shfl_xor(pel, 8); per += __shfl_xor(per, 8);
                if (l16 == 0) {
                    int rl = wm + mt * 16 + q * 4 + r;
                    elred[rl][wave >> 1][0] = pel;
                    elred[rl][wave >> 1][1] = per;
                }
            }
        __syncthreads();
        if (t < 64) {
            int row = row0 + t;
            if (row < M) {
                el[row * 4 + head] = elred[t][0][0] + elred[t][1][0];
                er[row * 4 + head] = elred[t][0][1] + elred[t][1][1];
            }
        }
    }
}

// ---------------- GAT aggregation body: 3-slot pipeline, no duplicate tail loads ----
template <bool RES, bool ACT, int EPI>
__device__ void agg_body(const ushort_t* __restrict__ feat,
                         const float* __restrict__ el,
                         const float* __restrict__ er,
                         const int* __restrict__ off,
                         const int* __restrict__ ss,
                         const ushort_t* residb,
                         const float* __restrict__ bias,
                         ushort_t* hl, int blk) {
    const int node = blk * 4 + ((int)threadIdx.x >> 6);
    const int lane = threadIdx.x & 63;
    if (node >= kN) return;
    const int off0 = off[node];
    const int deg = off[node + 1] - off0;
    float4 er4 = *(const float4*)(er + node * 4);
    const int head = lane >> 4;
    const float erh = (head == 0) ? er4.x : (head == 1) ? er4.y : (head == 2) ? er4.z : er4.w;
    const int c0 = lane * 8;
    const ushort_t* fbase = feat + c0;

    float den = 0.f;
    float acc[8] = {};
    if (deg > 0) {
        float e0[4], e1[4], e2[4];
        uint4 f0[4], f1[4], f2[4];
        auto LD = [&](int bj, float* ev, uint4* fv) {
#pragma unroll
            for (int i = 0; i < 4; ++i) {
                int idx = bj + i;
                if (idx < deg) {
                    int s = ss[off0 + idx];
                    ev[i] = el[s * 4 + head];
                    fv[i] = *(const uint4*)(fbase + (size_t)s * 512);
                }
            }
        };
        auto CONS = [&](int bj, const float* ev, const uint4* fv) {
#pragma unroll
            for (int i = 0; i < 4; ++i) {
                if (bj + i < deg) {
                    float w = __expf(lrelu(ev[i] + erh));
                    den += w;
                    acc[0] += w * bl(fv[i].x); acc[1] += w * bh(fv[i].x);
                    acc[2] += w * bl(fv[i].y); acc[3] += w * bh(fv[i].y);
                    acc[4] += w * bl(fv[i].z); acc[5] += w * bh(fv[i].z);
                    acc[6] += w * bl(fv[i].w); acc[7] += w * bh(fv[i].w);
                }
            }
        };
        LD(0, e0, f0);
        LD(4, e1, f1);
        LD(8, e2, f2);
        for (int j = 0; j < deg; j += 12) {
            CONS(j, e0, f0);
            if (j + 12 < deg) LD(j + 12, e0, f0);
            CONS(j + 4, e1, f1);
            if (j + 16 < deg) LD(j + 16, e1, f1);
            CONS(j + 8, e2, f2);
            if (j + 20 < deg) LD(j + 20, e2, f2);
        }
    }
    const float inv = 1.f / fmaxf(den, 1e-9f);
    float4 b0 = *(const float4*)(bias + c0);
    float4 b1 = *(const float4*)(bias + c0 + 4);
    float v[8];
#pragma unroll
    for (int r = 0; r < 8; ++r) v[r] = acc[r] * inv;
    v[0] += b0.x; v[1] += b0.y; v[2] += b0.z; v[3] += b0.w;
    v[4] += b1.x; v[5] += b1.y; v[6] += b1.z; v[7] += b1.w;
    if (RES) {
        uint4 rv = *(const uint4*)(residb + (size_t)node * 512 + c0);
        v[0] += bl(rv.x); v[1] += bh(rv.x);
        v[2] += bl(rv.y); v[3] += bh(rv.y);
        v[4] += bl(rv.z); v[5] += bh(rv.z);
        v[6] += bl(rv.w); v[7] += bh(rv.w);
    }
    if (ACT) {
#pragma unroll
        for (int r = 0; r < 8; ++r) v[r] = elu_f(v[r]);
    }
    if (EPI == 1) {
        ushort_t* hp = hl + (size_t)node * 512 + c0;
        ushort4 h0 = {f2b(v[0]), f2b(v[1]), f2b(v[2]), f2b(v[3])};
        ushort4 h1 = {f2b(v[4]), f2b(v[5]), f2b(v[6]), f2b(v[7])};
        *(ushort4*)hp = h0;
        *(ushort4*)(hp + 4) = h1;
    }
    if (EPI == 2) {
        float m[8];
#pragma unroll
        for (int r = 0; r < 8; ++r) {
            float x = v[r] + __shfl_xor(v[r], 16);
            x += __shfl_xor(x, 32);
            m[r] = 0.25f * x;
        }
        if (lane < 16) {
            ushort_t* hp = hl + (size_t)node * 128 + lane * 8;
            ushort4 h0 = {f2b(m[0]), f2b(m[1]), f2b(m[2]), f2b(m[3])};
            ushort4 h1 = {f2b(m[4]), f2b(m[5]), f2b(m[6]), f2b(m[7])};
            *(ushort4*)hp = h0;
            *(ushort4*)(hp + 4) = h1;
        }
    }
}

// ---------------- K2: prep || scan || fill || GEMM0, one launch ----------------
// __launch_bounds__(256,4) guarantees >=4 blocks/CU resident (1024 slots) so the
// 786 spinner blocks (scan+fill+G0) can never starve the 3990 prep producers.
__global__ __launch_bounds__(256, 4) void k_front(FrontArgs a) {
    const int b = blockIdx.x;
    if (b < kNP) {
        // prep: flags written by K1 (kernel boundary -> visible)
        const int f32in = a.flags[0];
        const int idx64 = a.flags[1];
        int i = b * 256 + threadIdx.x;
        if (i < kPrepTotal) prep_item(a, i, f32in, idx64);
        signal_done(&a.flags[3]);
        return;
    }
    if (b == kNP) {
        // scan: wait for all prep blocks (deg complete)
        spin_eq(&a.flags[3], kNP);
        __shared__ int s[256];
        int tid = threadIdx.x;
        int per = (kN + 255) / 256;   // 40
        int base0 = tid * per;
        int sum = 0;
        for (int i = 0; i < per; ++i) { int j = base0 + i; if (j < kN) sum += a.deg[j]; }
        s[tid] = sum;
        __syncthreads();
        for (int d = 1; d < 256; d <<= 1) {
            int v = (tid >= d) ? s[tid - d] : 0;
            __syncthreads();
            s[tid] += v;
            __syncthreads();
        }
        int run = (tid > 0) ? s[tid - 1] : 0;
        for (int i = 0; i < per; ++i) {
            int j = base0 + i;
            if (j < kN) { a.off[j] = run; run += a.deg[j]; }
        }
        if (tid == 255) a.off[kN] = s[255];
        __threadfence();
        __syncthreads();
        if (tid == 0) atomicExch(&a.flags[4], (int)kMagicB);
        return;
    }
    if (b < kNP + 1 + kFillChunks) {
        // fill: wait for scan (off complete)
        if (threadIdx.x == 0) {
            while ((unsigned)atomicAdd(&a.flags[4], 0) != kMagicB) __builtin_amdgcn_s_sleep(8);
        }
        __syncthreads();
        __threadfence();
        int chunk = b - (kNP + 1);
        int* cnt = a.deg + kN;
        for (int u = 0; u < 4; ++u) {
            int i = chunk * 1024 + u * 256 + threadIdx.x;
            if (i < kE) {
                int d = a.ndst[i];
                int pos = a.off[d] + atomicAdd(&cnt[d], 1);
                if (pos < kE) { a.ss[pos] = a.nsrc[i]; a.eid[pos] = i; a.dpos[pos] = d; }
            }
        }
        return;
    }
    // GEMM0: needs smallb + W0T (prep) only
    spin_eq(&a.flags[3], kNP);
    int r = b - (kNP + 1 + kFillChunks);
    gemm_body<true>(a.X, a.flags, 1, a.W0T, a.Fb, kN, 512, 256,
                    a.al0, a.ar0, a.el, a.er, r & 3, r >> 2);
}

// ---------------- K3/K4/K5: agg layer + following GEMM, one launch each ----------
// agg blocks signal ctr; GEMM blocks spin until all kGa aggs done (no aliasing race).
// __launch_bounds__(256,3) -> >=768 resident slots > 628 GEMM spinners.
template <bool RES, bool ACT, int EPI, bool GELER, int GXLOG>
__global__ __launch_bounds__(256, 3) void k_agg_gemm(
        const ushort_t* __restrict__ feat, const float* __restrict__ el_in,
        const float* __restrict__ er_in, const int* __restrict__ off,
        const int* __restrict__ ss, const ushort_t* residb,
        const float* __restrict__ bias, ushort_t* __restrict__ hl,
        const void* __restrict__ GA, const int* __restrict__ gflags,
        const ushort_t* __restrict__ GWT, ushort_t* __restrict__ GC,
        int GN, int GK,
        const float* __restrict__ gal, const float* __restrict__ gar,
        float* __restrict__ gel, float* __restrict__ ger,
        int* ctr) {
    const int b = blockIdx.x;
    if (b < kGa) {
        agg_body<RES, ACT, EPI>(feat, el_in, er_in, off, ss, residb, bias, hl, b);
        signal_done(ctr);
        return;
    }
    spin_eq(ctr, kGa);
    int r = b - kGa;
    gemm_body<GELER>(GA, gflags, 0, GWT, GC, kN, GN, GK,
                     gal, gar, gel, ger, r & ((1 << GXLOG) - 1), r >> GXLOG);
}

// ---------------- K6: MFMA edge MLP ----------------
__global__ __launch_bounds__(256) void edge_mfma(const ushort_t* __restrict__ PQb,
                                                 const float* __restrict__ bm0f,
                                                 const ushort_t* __restrict__ Wm1T,
                                                 const float* __restrict__ bm1f,
                                                 const float* __restrict__ wm2f,
                                                 const float* __restrict__ bm2f,
                                                 const int* __restrict__ ss,
                                                 const int* __restrict__ dpos,
                                                 const int* __restrict__ eid,
                                                 void* __restrict__ outv,
                                                 const int* __restrict__ flags) {
    const int t = threadIdx.x;
    const int wave = t >> 6, lane = t & 63;
    const int l16 = lane & 15, q = lane >> 4;
    const int base = blockIdx.x * 64 + wave * 16;
    const int pos = base + l16;
    const int s = ss[pos], d = dpos[pos];
    const ushort_t* prow = PQb + (size_t)s * 256;
    const ushort_t* qrow = PQb + (size_t)d * 256 + 128;

    f32x4 acc[4];
#pragma unroll
    for (int nt = 0; nt < 4; ++nt)
#pragma unroll
        for (int r = 0; r < 4; ++r) acc[nt][r] = 0.f;

#pragma unroll
    for (int ks = 0; ks < 4; ++ks) {
        const int k0 = ks * 32 + q * 8;
        uint4 pv = *(const uint4*)(prow + k0);
        uint4 qv = *(const uint4*)(qrow + k0);
        float4 bb0 = *(const float4*)(bm0f + k0);
        float4 bb1 = *(const float4*)(bm0f + k0 + 4);
        v8s a;
        a[0] = (short)f2b(fmaxf(bl(pv.x) + bl(qv.x) + bb0.x, 0.f));
        a[1] = (short)f2b(fmaxf(bh(pv.x) + bh(qv.x) + bb0.y, 0.f));
        a[2] = (short)f2b(fmaxf(bl(pv.y) + bl(qv.y) + bb0.z, 0.f));
        a[3] = (short)f2b(fmaxf(bh(pv.y) + bh(qv.y) + bb0.w, 0.f));
        a[4] = (short)f2b(fmaxf(bl(pv.z) + bl(qv.z) + bb1.x, 0.f));
        a[5] = (short)f2b(fmaxf(bh(pv.z) + bh(qv.z) + bb1.y, 0.f));
        a[6] = (short)f2b(fmaxf(bl(pv.w) + bl(qv.w) + bb1.z, 0.f));
        a[7] = (short)f2b(fmaxf(bh(pv.w) + bh(qv.w) + bb1.w, 0.f));
#pragma unroll
        for (int nt = 0; nt < 4; ++nt) {
            v8s b = *(const v8s*)(Wm1T + (size_t)(nt * 16 + l16) * 128 + k0);
            acc[nt] = __builtin_amdgcn_mfma_f32_16x16x32_bf16(a, b, acc[nt], 0, 0, 0);
        }
    }
    float b1v[4], w2v[4];
#pragma unroll
    for (int nt = 0; nt < 4; ++nt) {
        b1v[nt] = bm1f[nt * 16 + l16];
        w2v[nt] = wm2f[nt * 16 + l16];
    }
    float b2 = bm2f[0];
    const int f32out = flags[0];
#pragma unroll
    for (int r = 0; r < 4; ++r) {
        float v = 0.f;
#pragma unroll
        for (int nt = 0; nt < 4; ++nt)
            v += fmaxf(acc[nt][r] + b1v[nt], 0.f) * w2v[nt];
        v += __shfl_xor(v, 1);
        v += __shfl_xor(v, 2);
        v += __shfl_xor(v, 4);
        v += __shfl_xor(v, 8);
        if (l16 == 0) {
            int e = eid[base + q * 4 + r];
            float rr = 1.f / (1.f + __expf(-(v + b2)));
            if (f32out) ((float*)outv)[e] = rr;
            else        ((ushort_t*)outv)[e] = f2b(rr);
        }
    }
}

// ---------------- host launch ----------------
extern "C" void kernel_launch(void* const* d_in, const int* in_sizes, int n_in,
                              void* d_out, int out_size, void* d_ws, size_t ws_size,
                              hipStream_t stream) {
    (void)in_sizes; (void)n_in; (void)out_size; (void)ws_size;

    float* w = (float*)d_ws;
    size_t o = 0;
    auto alloc = [&](size_t n) { float* p = w + o; o += (n + 3) & ~size_t(3); return p; };
    float* smallb = alloc(4868);
    float* al0f = smallb + 0;    float* ar0f = smallb + 512;  float* b0f  = smallb + 1024;
    float* al1f = smallb + 1536; float* ar1f = smallb + 2048; float* b1f  = smallb + 2560;
    float* al2f = smallb + 3072; float* ar2f = smallb + 3584; float* b2f_ = smallb + 4096;
    float* bm0f = smallb + 4608; float* bm1f = smallb + 4736;
    float* wm2f = smallb + 4800; float* bm2f = smallb + 4864;
    float* elb  = alloc((size_t)kN * 4);
    float* erb  = alloc((size_t)kN * 4);
    ushort_t* Fb  = (ushort_t*)alloc((size_t)kN * 256);      // bf16 feat [10000][512]
    ushort_t* AHL = (ushort_t*)alloc((size_t)kN * 256);      // bf16 layer act [10000][512]
    ushort_t* MHb = (ushort_t*)alloc((size_t)kN * 64);       // bf16 head-mean [10000][128]
    ushort_t* W0T  = (ushort_t*)alloc(65536);                // [512][256]
    ushort_t* W1T  = (ushort_t*)alloc(131072);               // [512][512]
    ushort_t* W2T  = (ushort_t*)alloc(131072);               // [512][512]
    ushort_t* PQT  = (ushort_t*)alloc(16384);                // [256][128]
    ushort_t* Wm1T = (ushort_t*)alloc(4096);                 // [64][128]
    int* ip    = (int*)(w + o);
    int* flags = ip;            // 8 ints (incl. sync counters)
    int* deg   = ip + 8;
    int* cnt   = deg + kN;
    int* off   = cnt + kN;
    int* ss    = off + 10004;
    int* eid   = ss + kE;
    int* dpos  = eid + kE;
    int* nsrc  = dpos + kE;
    int* ndst  = nsrc + kE;

    ushort_t* PQb = Fb;   // bf16 [10000][256] P|Q; written after L2 agg frees Fb

    dim3 blk(256);

    // K1: flags + deg/cnt + sync-counter zeroing
    detect_zero<<<dim3(1 + (2 * kN + 255) / 256), blk, 0, stream>>>(d_in[0], d_in[2], flags, deg);

    // K2: prep || CSR scan || CSR fill || GEMM0 (f32->bf16 staging from d_in[0])
    FrontArgs a;
    const int sidx[13] = {4, 5, 6, 8, 9, 10, 12, 13, 14, 16, 18, 19, 20};
    for (int i = 0; i < 13; ++i) a.sm[i] = d_in[sidx[i]];
    a.W0 = d_in[3]; a.W1 = d_in[7]; a.W2 = d_in[11]; a.Wm0 = d_in[15]; a.Wm1 = d_in[17];
    a.X = d_in[0]; a.srcIn = d_in[1]; a.dstIn = d_in[2];
    a.smallb = smallb; a.W0T = W0T; a.W1T = W1T; a.W2T = W2T; a.PQT = PQT; a.Wm1T = Wm1T;
    a.nsrc = nsrc; a.ndst = ndst;
    a.flags = flags; a.deg = deg; a.off = off; a.ss = ss; a.eid = eid; a.dpos = dpos;
    a.Fb = Fb; a.al0 = al0f; a.ar0 = ar0f; a.el = elb; a.er = erb;
    k_front<<<dim3(kNP + 1 + kFillChunks + 4 * kGy), blk, 0, stream>>>(a);

    // K3: agg layer0 + GEMM1 (spins on agg0 counter)
    k_agg_gemm<false, true, 1, true, 2><<<dim3(kGa + 4 * kGy), blk, 0, stream>>>(
        Fb, elb, erb, off, ss, nullptr, b0f, AHL,
        AHL, flags, W1T, Fb, 512, 512, al1f, ar1f, elb, erb, &flags[5]);

    // K4: agg layer1 (resid, ELU, in-place) + GEMM2
    k_agg_gemm<true, true, 1, true, 2><<<dim3(kGa + 4 * kGy), blk, 0, stream>>>(
        Fb, elb, erb, off, ss, AHL, b1f, AHL,
        AHL, flags, W2T, Fb, 512, 512, al2f, ar2f, elb, erb, &flags[6]);

    // K5: agg layer2 (resid, head-mean) + PQ GEMM (PQb overlays Fb; waits all agg2)
    k_agg_gemm<true, false, 2, false, 1><<<dim3(kGa + 2 * kGy), blk, 0, stream>>>(
        Fb, elb, erb, off, ss, AHL, b2f_, MHb,
        MHb, flags, PQT, PQb, 256, 128, nullptr, nullptr, nullptr, nullptr, &flags[7]);

    // K6: edge MLP + sigmoid
    edge_mfma<<<dim3(kE / 64), blk, 0, stream>>>(PQb, bm0f, Wm1T, bm1f, wm2f, bm2f,
                                                 ss, dpos, eid, d_out, flags);
}

// Round 7
// 335.393 us; speedup vs baseline: 5.7815x; 5.7815x over previous
//
#include <hip/hip_runtime.h>
#include <hip/hip_bf16.h>
#include <math.h>

constexpr int kN = 10000;   // nodes
constexpr int kE = 160000;  // edges
constexpr float kSlope = 0.2f;

typedef short v8s __attribute__((ext_vector_type(8)));
typedef float f32x4 __attribute__((ext_vector_type(4)));
typedef unsigned short ushort_t;

__device__ __forceinline__ float lrelu(float x) { return x > 0.f ? x : kSlope * x; }
__device__ __forceinline__ float elu_f(float x) { return x > 0.f ? x : (__expf(x) - 1.f); }
__device__ __forceinline__ float b2f(ushort_t u) {
    return __uint_as_float(((unsigned)u) << 16);
}
__device__ __forceinline__ float bl(unsigned u) { return __uint_as_float(u << 16); }
__device__ __forceinline__ float bh(unsigned u) { return __uint_as_float(u & 0xffff0000u); }
__device__ __forceinline__ ushort_t f2b(float f) {   // RNE f32->bf16
    unsigned u = __float_as_uint(f);
    return (ushort_t)((u + 0x7FFFu + ((u >> 16) & 1u)) >> 16);
}

// bijective XCD-chunked swizzle (m204): dispatch id s -> logical tile id.
// XCD x gets a CONTIGUOUS chunk of tiles (L2 locality for shared A-panels).
__device__ __forceinline__ int xcd_swz(int s, int nwg) {
    int q = nwg >> 3, rm = nwg & 7;
    int x = s & 7, j = s >> 3;
    return (x < rm) ? x * (q + 1) + j : rm * (q + 1) + (x - rm) * q + j;
}

// ---------------- dtype detection + deg/cnt zeroing (one launch) ----------------
__global__ void detect_zero(const void* __restrict__ x, const void* __restrict__ dsti,
                            int* __restrict__ flags, int* __restrict__ deg) {
    if (blockIdx.x == 0) {
        __shared__ int sb[2];
        int tid = threadIdx.x;
        if (tid == 0) { sb[0] = 0; sb[1] = 0; }
        __syncthreads();
        const ushort_t* xb = (const ushort_t*)x;
        int big = 0;
        for (int i = tid; i < 4096; i += 256) {
            float v = b2f(xb[i]);
            if (!(fabsf(v) <= 1e4f)) big = 1;
        }
        const int* d32 = (const int*)dsti;
        int hi = 0;
        for (int i = tid; i < 4096; i += 256) hi |= d32[2 * i + 1];
        if (big) atomicOr(&sb[0], 1);
        if (hi)  atomicOr(&sb[1], 1);
        __syncthreads();
        if (tid == 0) { flags[0] = sb[0]; flags[1] = sb[1] ? 0 : 1; }
    } else {
        int i = (blockIdx.x - 1) * 256 + threadIdx.x;
        if (i < 2 * kN) deg[i] = 0;    // deg + cnt contiguous
    }
}

// ---------------- all flag-dependent prep in ONE launch (no Xb pass) ----------------
struct PrepArgs {
    const void* sm[13];
    const void* W0; const void* W1; const void* W2; const void* Wm0; const void* Wm1;
    const void* srcIn; const void* dstIn;
    float* smallb;
    ushort_t* W0T; ushort_t* W1T; ushort_t* W2T; ushort_t* PQT; ushort_t* Wm1T;
    int* nsrc; int* ndst; int* deg;
    const int* flags;
};
// segments: 4865 | 131072 | 262144 | 262144 | 32768 | 8192 | 320000
constexpr int kPrepTotal = 4865 + 131072 + 262144 + 262144 + 32768 + 8192 + 320000;

__global__ void prep_all(PrepArgs a) {
    int i = blockIdx.x * 256 + threadIdx.x;
    if (i >= kPrepTotal) return;
    const int f32in = a.flags[0];
    auto cv = [&](const void* p, int idx) -> ushort_t {
        return f32in ? f2b(((const float*)p)[idx]) : ((const ushort_t*)p)[idx];
    };
    if (i < 4865) {   // small f32 tensors
        int seg, offi;
        if (i < 4608)      { seg = i >> 9; offi = i & 511; }
        else if (i < 4736) { seg = 9;  offi = i - 4608; }
        else if (i < 4800) { seg = 10; offi = i - 4736; }
        else if (i < 4864) { seg = 11; offi = i - 4800; }
        else               { seg = 12; offi = 0; }
        a.smallb[i] = f32in ? ((const float*)a.sm[seg])[offi]
                            : b2f(((const ushort_t*)a.sm[seg])[offi]);
        return;
    }
    i -= 4865;
    if (i < 131072) {   // W0T [512][256]
        int n = i >> 8, k = i & 255;
        a.W0T[i] = cv(a.W0, k * 512 + n);
        return;
    }
    i -= 131072;
    if (i < 262144) {   // W1T [512][512]
        int n = i >> 9, k = i & 511;
        a.W1T[i] = cv(a.W1, k * 512 + n);
        return;
    }
    i -= 262144;
    if (i < 262144) {   // W2T [512][512]
        int n = i >> 9, k = i & 511;
        a.W2T[i] = cv(a.W2, k * 512 + n);
        return;
    }
    i -= 262144;
    if (i < 32768) {    // PQT [256][128]
        int n = i >> 7, k = i & 127;
        a.PQT[i] = cv(a.Wm0, (k + ((n < 128) ? 0 : 128)) * 128 + (n & 127));
        return;
    }
    i -= 32768;
    if (i < 8192) {     // Wm1T [64][128]
        int n = i >> 7, k = i & 127;
        a.Wm1T[i] = cv(a.Wm1, k * 64 + n);
        return;
    }
    i -= 8192;
    {                   // index normalize + degree count
        const void* in = (i < kE) ? a.srcIn : a.dstIn;
        int j = (i < kE) ? i : i - kE;
        int v = a.flags[1] ? (int)((const long long*)in)[j] : ((const int*)in)[j];
        v = ((unsigned)v < (unsigned)kN) ? v : 0;
        if (i < kE) a.nsrc[j] = v;
        else { a.ndst[j] = v; atomicAdd(&a.deg[v], 1); }
    }
}

// ---------------- CSR build ----------------
__global__ __launch_bounds__(1024) void scan_off(const int* __restrict__ deg,
                                                 int* __restrict__ off, int n) {
    __shared__ int s[1024];
    int tid = threadIdx.x;
    int per = (n + 1023) >> 10;
    int base = tid * per;
    int sum = 0;
    for (int i = 0; i < per; ++i) { int j = base + i; if (j < n) sum += deg[j]; }
    s[tid] = sum;
    __syncthreads();
    for (int d = 1; d < 1024; d <<= 1) {
        int v = (tid >= d) ? s[tid - d] : 0;
        __syncthreads();
        s[tid] += v;
        __syncthreads();
    }
    int run = (tid > 0) ? s[tid - 1] : 0;
    for (int i = 0; i < per; ++i) {
        int j = base + i;
        if (j < n) { off[j] = run; run += deg[j]; }
    }
    if (tid == 0) off[n] = s[1023];
}

__global__ void fill_csr(const int* __restrict__ src, const int* __restrict__ dst,
                         const int* __restrict__ off, int* __restrict__ cnt,
                         int* __restrict__ ss, int* __restrict__ eid,
                         int* __restrict__ dpos, int n) {
    int i = blockIdx.x * 256 + threadIdx.x;
    if (i < n) {
        int d = dst[i];
        int pos = off[d] + atomicAdd(&cnt[d], 1);
        if (pos < kE) { ss[pos] = src[i]; eid[pos] = i; dpos[pos] = d; }
    }
}

// ---------------- LDS-staged MFMA GEMM (R0-proven K-chunk-32 structure) ----------------
// 1D grid + bijective XCD-chunked swizzle: tile = xcd_swz(blockIdx.x, gridDim.x);
// bx = tile & (2^xlog - 1) (column panel / head), by = tile >> xlog (row tile).
// A [M,K] row-major: bf16, or f32 when (f32sel && gflags[0]) -> converted in-register.
// WT [N,K] bf16 row-major. C [M,N] bf16. ELER: fused el/er (head = bx).
template <bool ELER>
__global__ __launch_bounds__(256) void gemm_mfma(const void* __restrict__ A,
                                                 const int* __restrict__ gflags,
                                                 int f32sel, int xlog,
                                                 const ushort_t* __restrict__ WT,
                                                 ushort_t* __restrict__ Cout,
                                                 int M, int N, int K,
                                                 const float* __restrict__ al,
                                                 const float* __restrict__ ar,
                                                 float* __restrict__ el,
                                                 float* __restrict__ er) {
    __shared__ __align__(16) ushort_t As[4][64][8];
    __shared__ __align__(16) ushort_t Bs[4][128][8];
    __shared__ float elred[64][2][2];
    const int tile = xcd_swz(blockIdx.x, gridDim.x);
    const int bx = tile & ((1 << xlog) - 1), by = tile >> xlog;
    const int t = threadIdx.x;
    const int wave = t >> 6, lane = t & 63;
    const int l16 = lane & 15, q = lane >> 4;
    const int row0 = by * 64, col0 = bx * 128;
    const int wm = (wave & 1) * 32, wn = (wave >> 1) * 64;
    const int am = t >> 2, ak8 = t & 3;
    const int sw = ak8 * 4;

    const int f32a = f32sel && gflags[0];
    const size_t arow = (size_t)min(row0 + am, M - 1) * K + ak8 * 8;
    const ushort_t* aB = (const ushort_t*)A + arow;
    const float*    aF = (const float*)A + arow;
    const ushort_t* bptr0 = WT + (size_t)(col0 + am) * K + ak8 * 8;
    const ushort_t* bptr1 = bptr0 + (size_t)64 * K;

    auto loadA = [&](int k0) -> uint4 {
        if (!f32a) return *(const uint4*)(aB + k0);
        float4 f0 = *(const float4*)(aF + k0);
        float4 f1 = *(const float4*)(aF + k0 + 4);
        uint4 r;
        r.x = (unsigned)f2b(f0.x) | ((unsigned)f2b(f0.y) << 16);
        r.y = (unsigned)f2b(f0.z) | ((unsigned)f2b(f0.w) << 16);
        r.z = (unsigned)f2b(f1.x) | ((unsigned)f2b(f1.y) << 16);
        r.w = (unsigned)f2b(f1.z) | ((unsigned)f2b(f1.w) << 16);
        return r;
    };

    uint4 ga  = loadA(0);
    uint4 gb0 = *(const uint4*)bptr0;
    uint4 gb1 = *(const uint4*)bptr1;

    f32x4 acc[2][4];
#pragma unroll
    for (int mt = 0; mt < 2; ++mt)
#pragma unroll
        for (int nt = 0; nt < 4; ++nt)
#pragma unroll
            for (int r = 0; r < 4; ++r) acc[mt][nt][r] = 0.f;

    for (int k0 = 0; k0 < K; k0 += 32) {
        __syncthreads();
        *(uint4*)&As[ak8][am ^ sw][0] = ga;
        *(uint4*)&Bs[ak8][am ^ sw][0] = gb0;
        *(uint4*)&Bs[ak8][(am + 64) ^ sw][0] = gb1;
        __syncthreads();
        if (k0 + 32 < K) {
            ga  = loadA(k0 + 32);
            gb0 = *(const uint4*)(bptr0 + k0 + 32);
            gb1 = *(const uint4*)(bptr1 + k0 + 32);
        }
        v8s af[2], bf[4];
        const int qs = q * 4;
#pragma unroll
        for (int mt = 0; mt < 2; ++mt)
            af[mt] = *(const v8s*)&As[q][(wm + mt * 16 + l16) ^ qs][0];
#pragma unroll
        for (int nt = 0; nt < 4; ++nt)
            bf[nt] = *(const v8s*)&Bs[q][(wn + nt * 16 + l16) ^ qs][0];
#pragma unroll
        for (int mt = 0; mt < 2; ++mt)
#pragma unroll
            for (int nt = 0; nt < 4; ++nt)
                acc[mt][nt] = __builtin_amdgcn_mfma_f32_16x16x32_bf16(af[mt], bf[nt],
                                                                      acc[mt][nt], 0, 0, 0);
    }
#pragma unroll
    for (int mt = 0; mt < 2; ++mt)
#pragma unroll
        for (int r = 0; r < 4; ++r) {
            int row = row0 + wm + mt * 16 + q * 4 + r;
            if (row < M) {
#pragma unroll
                for (int nt = 0; nt < 4; ++nt)
                    Cout[(size_t)row * N + col0 + wn + nt * 16 + l16] = f2b(acc[mt][nt][r]);
            }
        }
    if (ELER) {
        const int head = bx;
        float alv[4], arv[4];
#pragma unroll
        for (int nt = 0; nt < 4; ++nt) {
            alv[nt] = al[head * 128 + wn + nt * 16 + l16];
            arv[nt] = ar[head * 128 + wn + nt * 16 + l16];
        }
#pragma unroll
        for (int mt = 0; mt < 2; ++mt)
#pragma unroll
            for (int r = 0; r < 4; ++r) {
                float pel = 0.f, per = 0.f;
#pragma unroll
                for (int nt = 0; nt < 4; ++nt) {
                    pel += acc[mt][nt][r] * alv[nt];
                    per += acc[mt][nt][r] * arv[nt];
                }
                pel += __shfl_xor(pel, 1); per += __shfl_xor(per, 1);
                pel += __shfl_xor(pel, 2); per += __shfl_xor(per, 2);
                pel += __shfl_xor(pel, 4); per += __shfl_xor(per, 4);
                pel += __shfl_xor(pel, 8); per += __shfl_xor(per, 8);
                if (l16 == 0) {
                    int rl = wm + mt * 16 + q * 4 + r;
                    elred[rl][wave >> 1][0] = pel;
                    elred[rl][wave >> 1][1] = per;
                }
            }
        __syncthreads();
        if (t < 64) {
            int row = row0 + t;
            if (row < M) {
                el[row * 4 + head] = elred[t][0][0] + elred[t][1][0];
                er[row * 4 + head] = elred[t][0][1] + elred[t][1][1];
            }
        }
    }
}

// ---------------- GAT softmax + aggregation: 3-slot pipeline, guarded tail loads ----
// softmax = (sum e*f)/(sum e); feat bf16; resid bf16 (may alias hl).
// EPI 1: write bf16 [node][512]; EPI 2: write head-mean bf16 [node][128].
template <bool RES, bool ACT, int EPI>
__global__ __launch_bounds__(256) void gat_agg(const ushort_t* __restrict__ feat,
                                               const float* __restrict__ el,
                                               const float* __restrict__ er,
                                               const int* __restrict__ off,
                                               const int* __restrict__ ss,
                                               const ushort_t* residb,
                                               const float* __restrict__ bias,
                                               ushort_t* hl) {
    const int node = blockIdx.x * 4 + (threadIdx.x >> 6);
    const int lane = threadIdx.x & 63;
    if (node >= kN) return;
    const int off0 = off[node];
    const int deg = off[node + 1] - off0;
    float4 er4 = *(const float4*)(er + node * 4);
    const int head = lane >> 4;
    const float erh = (head == 0) ? er4.x : (head == 1) ? er4.y : (head == 2) ? er4.z : er4.w;
    const int c0 = lane * 8;
    const ushort_t* fbase = feat + c0;

    float den = 0.f;
    float acc[8] = {};
    if (deg > 0) {
        float e0[4], e1[4], e2[4];
        uint4 f0[4], f1[4], f2[4];
        auto LD = [&](int bj, float* ev, uint4* fv) {
#pragma unroll
            for (int i = 0; i < 4; ++i) {
                int idx = bj + i;
                if (idx < deg) {
                    int s = ss[off0 + idx];
                    ev[i] = el[s * 4 + head];
                    fv[i] = *(const uint4*)(fbase + (size_t)s * 512);
                }
            }
        };
        auto CONS = [&](int bj, const float* ev, const uint4* fv) {
#pragma unroll
            for (int i = 0; i < 4; ++i) {
                if (bj + i < deg) {
                    float w = __expf(lrelu(ev[i] + erh));
                    den += w;
                    acc[0] += w * bl(fv[i].x); acc[1] += w * bh(fv[i].x);
                    acc[2] += w * bl(fv[i].y); acc[3] += w * bh(fv[i].y);
                    acc[4] += w * bl(fv[i].z); acc[5] += w * bh(fv[i].z);
                    acc[6] += w * bl(fv[i].w); acc[7] += w * bh(fv[i].w);
                }
            }
        };
        LD(0, e0, f0);
        LD(4, e1, f1);
        LD(8, e2, f2);
        for (int j = 0; j < deg; j += 12) {
            CONS(j, e0, f0);
            if (j + 12 < deg) LD(j + 12, e0, f0);
            CONS(j + 4, e1, f1);
            if (j + 16 < deg) LD(j + 16, e1, f1);
            CONS(j + 8, e2, f2);
            if (j + 20 < deg) LD(j + 20, e2, f2);
        }
    }
    const float inv = 1.f / fmaxf(den, 1e-9f);
    float4 b0 = *(const float4*)(bias + c0);
    float4 b1 = *(const float4*)(bias + c0 + 4);
    float v[8];
#pragma unroll
    for (int r = 0; r < 8; ++r) v[r] = acc[r] * inv;
    v[0] += b0.x; v[1] += b0.y; v[2] += b0.z; v[3] += b0.w;
    v[4] += b1.x; v[5] += b1.y; v[6] += b1.z; v[7] += b1.w;
    if (RES) {
        uint4 rv = *(const uint4*)(residb + (size_t)node * 512 + c0);
        v[0] += bl(rv.x); v[1] += bh(rv.x);
        v[2] += bl(rv.y); v[3] += bh(rv.y);
        v[4] += bl(rv.z); v[5] += bh(rv.z);
        v[6] += bl(rv.w); v[7] += bh(rv.w);
    }
    if (ACT) {
#pragma unroll
        for (int r = 0; r < 8; ++r) v[r] = elu_f(v[r]);
    }
    if (EPI == 1) {
        ushort_t* hp = hl + (size_t)node * 512 + c0;
        ushort4 h0 = {f2b(v[0]), f2b(v[1]), f2b(v[2]), f2b(v[3])};
        ushort4 h1 = {f2b(v[4]), f2b(v[5]), f2b(v[6]), f2b(v[7])};
        *(ushort4*)hp = h0;
        *(ushort4*)(hp + 4) = h1;
    }
    if (EPI == 2) {
        float m[8];
#pragma unroll
        for (int r = 0; r < 8; ++r) {
            float x = v[r] + __shfl_xor(v[r], 16);
            x += __shfl_xor(x, 32);
            m[r] = 0.25f * x;
        }
        if (lane < 16) {
            ushort_t* hp = hl + (size_t)node * 128 + lane * 8;
            ushort4 h0 = {f2b(m[0]), f2b(m[1]), f2b(m[2]), f2b(m[3])};
            ushort4 h1 = {f2b(m[4]), f2b(m[5]), f2b(m[6]), f2b(m[7])};
            *(ushort4*)hp = h0;
            *(ushort4*)(hp + 4) = h1;
        }
    }
}

// ---------------- MFMA edge MLP: LDS-free direct-fragment gather ----------------
__global__ __launch_bounds__(256) void edge_mfma(const ushort_t* __restrict__ PQb,
                                                 const float* __restrict__ bm0f,
                                                 const ushort_t* __restrict__ Wm1T,
                                                 const float* __restrict__ bm1f,
                                                 const float* __restrict__ wm2f,
                                                 const float* __restrict__ bm2f,
                                                 const int* __restrict__ ss,
                                                 const int* __restrict__ dpos,
                                                 const int* __restrict__ eid,
                                                 void* __restrict__ outv,
                                                 const int* __restrict__ flags) {
    const int t = threadIdx.x;
    const int wave = t >> 6, lane = t & 63;
    const int l16 = lane & 15, q = lane >> 4;
    const int base = blockIdx.x * 64 + wave * 16;
    const int pos = base + l16;
    const int s = ss[pos], d = dpos[pos];
    const ushort_t* prow = PQb + (size_t)s * 256;
    const ushort_t* qrow = PQb + (size_t)d * 256 + 128;

    f32x4 acc[4];
#pragma unroll
    for (int nt = 0; nt < 4; ++nt)
#pragma unroll
        for (int r = 0; r < 4; ++r) acc[nt][r] = 0.f;

#pragma unroll
    for (int ks = 0; ks < 4; ++ks) {
        const int k0 = ks * 32 + q * 8;
        uint4 pv = *(const uint4*)(prow + k0);
        uint4 qv = *(const uint4*)(qrow + k0);
        float4 bb0 = *(const float4*)(bm0f + k0);
        float4 bb1 = *(const float4*)(bm0f + k0 + 4);
        v8s a;
        a[0] = (short)f2b(fmaxf(bl(pv.x) + bl(qv.x) + bb0.x, 0.f));
        a[1] = (short)f2b(fmaxf(bh(pv.x) + bh(qv.x) + bb0.y, 0.f));
        a[2] = (short)f2b(fmaxf(bl(pv.y) + bl(qv.y) + bb0.z, 0.f));
        a[3] = (short)f2b(fmaxf(bh(pv.y) + bh(qv.y) + bb0.w, 0.f));
        a[4] = (short)f2b(fmaxf(bl(pv.z) + bl(qv.z) + bb1.x, 0.f));
        a[5] = (short)f2b(fmaxf(bh(pv.z) + bh(qv.z) + bb1.y, 0.f));
        a[6] = (short)f2b(fmaxf(bl(pv.w) + bl(qv.w) + bb1.z, 0.f));
        a[7] = (short)f2b(fmaxf(bh(pv.w) + bh(qv.w) + bb1.w, 0.f));
#pragma unroll
        for (int nt = 0; nt < 4; ++nt) {
            v8s b = *(const v8s*)(Wm1T + (size_t)(nt * 16 + l16) * 128 + k0);
            acc[nt] = __builtin_amdgcn_mfma_f32_16x16x32_bf16(a, b, acc[nt], 0, 0, 0);
        }
    }
    float b1v[4], w2v[4];
#pragma unroll
    for (int nt = 0; nt < 4; ++nt) {
        b1v[nt] = bm1f[nt * 16 + l16];
        w2v[nt] = wm2f[nt * 16 + l16];
    }
    float b2 = bm2f[0];
    const int f32out = flags[0];
#pragma unroll
    for (int r = 0; r < 4; ++r) {
        float v = 0.f;
#pragma unroll
        for (int nt = 0; nt < 4; ++nt)
            v += fmaxf(acc[nt][r] + b1v[nt], 0.f) * w2v[nt];
        v += __shfl_xor(v, 1);
        v += __shfl_xor(v, 2);
        v += __shfl_xor(v, 4);
        v += __shfl_xor(v, 8);
        if (l16 == 0) {
            int e = eid[base + q * 4 + r];
            float rr = 1.f / (1.f + __expf(-(v + b2)));
            if (f32out) ((float*)outv)[e] = rr;
            else        ((ushort_t*)outv)[e] = f2b(rr);
        }
    }
}

// ---------------- host launch ----------------
extern "C" void kernel_launch(void* const* d_in, const int* in_sizes, int n_in,
                              void* d_out, int out_size, void* d_ws, size_t ws_size,
                              hipStream_t stream) {
    (void)in_sizes; (void)n_in; (void)out_size; (void)ws_size;

    float* w = (float*)d_ws;
    size_t o = 0;
    auto alloc = [&](size_t n) { float* p = w + o; o += (n + 3) & ~size_t(3); return p; };
    float* smallb = alloc(4868);
    float* al0f = smallb + 0;    float* ar0f = smallb + 512;  float* b0f  = smallb + 1024;
    float* al1f = smallb + 1536; float* ar1f = smallb + 2048; float* b1f  = smallb + 2560;
    float* al2f = smallb + 3072; float* ar2f = smallb + 3584; float* b2f_ = smallb + 4096;
    float* bm0f = smallb + 4608; float* bm1f = smallb + 4736;
    float* wm2f = smallb + 4800; float* bm2f = smallb + 4864;
    float* elb  = alloc((size_t)kN * 4);
    float* erb  = alloc((size_t)kN * 4);
    ushort_t* Fb  = (ushort_t*)alloc((size_t)kN * 256);      // bf16 feat [10000][512]
    ushort_t* AHL = (ushort_t*)alloc((size_t)kN * 256);      // bf16 layer act [10000][512]
    ushort_t* MHb = (ushort_t*)alloc((size_t)kN * 64);       // bf16 head-mean [10000][128]
    ushort_t* W0T  = (ushort_t*)alloc(65536);                // [512][256]
    ushort_t* W1T  = (ushort_t*)alloc(131072);               // [512][512]
    ushort_t* W2T  = (ushort_t*)alloc(131072);               // [512][512]
    ushort_t* PQT  = (ushort_t*)alloc(16384);                // [256][128]
    ushort_t* Wm1T = (ushort_t*)alloc(4096);                 // [64][128]
    int* ip    = (int*)(w + o);
    int* flags = ip;
    int* deg   = ip + 4;
    int* cnt   = deg + kN;
    int* off   = cnt + kN;
    int* ss    = off + 10004;
    int* eid   = ss + kE;
    int* dpos  = eid + kE;
    int* nsrc  = dpos + kE;
    int* ndst  = nsrc + kE;

    ushort_t* PQb = Fb;   // bf16 [10000][256] P|Q; written after L2 agg frees Fb

    dim3 blk(256);

    // 0) flags + deg/cnt zero
    detect_zero<<<dim3(1 + (2 * kN + 255) / 256), blk, 0, stream>>>(d_in[0], d_in[2], flags, deg);

    // 1) all flag-dependent prep + index normalize + degree count (no Xb pass)
    PrepArgs a;
    const int sidx[13] = {4, 5, 6, 8, 9, 10, 12, 13, 14, 16, 18, 19, 20};
    for (int i = 0; i < 13; ++i) a.sm[i] = d_in[sidx[i]];
    a.W0 = d_in[3]; a.W1 = d_in[7]; a.W2 = d_in[11]; a.Wm0 = d_in[15]; a.Wm1 = d_in[17];
    a.srcIn = d_in[1]; a.dstIn = d_in[2];
    a.smallb = smallb; a.W0T = W0T; a.W1T = W1T; a.W2T = W2T; a.PQT = PQT; a.Wm1T = Wm1T;
    a.nsrc = nsrc; a.ndst = ndst; a.deg = deg; a.flags = flags;
    prep_all<<<dim3((kPrepTotal + 255) / 256), blk, 0, stream>>>(a);

    // 2) CSR scan + fill
    scan_off<<<dim3(1), dim3(1024), 0, stream>>>(deg, off, kN);
    fill_csr<<<dim3((kE + 255) / 256), blk, 0, stream>>>(nsrc, ndst, off, cnt, ss, eid, dpos, kE);

    const int gy = (kN + 63) / 64;      // 157 row tiles
    const int ga = (kN + 3) / 4;        // 2500 agg blocks

    // 3) Layer 0: Fb = x @ W0 (+ fused el/er); A = d_in[0], f32->bf16 in staging
    gemm_mfma<true><<<dim3(4 * gy), blk, 0, stream>>>(d_in[0], flags, 1, 2, W0T, Fb,
                                                      kN, 512, 256, al0f, ar0f, elb, erb);
    gat_agg<false, true, 1><<<dim3(ga), blk, 0, stream>>>(Fb, elb, erb, off, ss,
                                                          nullptr, b0f, AHL);

    // 4) Layer 1 (residual, ELU): AHL @ W1, K=512; in-place bf16 resid+out
    gemm_mfma<true><<<dim3(4 * gy), blk, 0, stream>>>(AHL, flags, 0, 2, W1T, Fb,
                                                      kN, 512, 512, al1f, ar1f, elb, erb);
    gat_agg<true, true, 1><<<dim3(ga), blk, 0, stream>>>(Fb, elb, erb, off, ss,
                                                         AHL, b1f, AHL);

    // 5) Layer 2 (residual, no act) + fused head-mean bf16
    gemm_mfma<true><<<dim3(4 * gy), blk, 0, stream>>>(AHL, flags, 0, 2, W2T, Fb,
                                                      kN, 512, 512, al2f, ar2f, elb, erb);
    gat_agg<true, false, 2><<<dim3(ga), blk, 0, stream>>>(Fb, elb, erb, off, ss,
                                                          AHL, b2f_, MHb);

    // 6) PQb (bf16) = head-mean @ [Wm0_top | Wm0_bot], K=128  (PQb overlays Fb)
    gemm_mfma<false><<<dim3(2 * gy), blk, 0, stream>>>(MHb, flags, 0, 1, PQT, PQb,
                                                       kN, 256, 128,
                                                       nullptr, nullptr, nullptr, nullptr);

    // 7) LDS-free edge MLP + sigmoid
    edge_mfma<<<dim3(kE / 64), blk, 0, stream>>>(PQb, bm0f, Wm1T, bm1f, wm2f, bm2f,
                                                 ss, dpos, eid, d_out, flags);
}

// Round 8
// 317.529 us; speedup vs baseline: 6.1068x; 1.0563x over previous
//
#include <hip/hip_runtime.h>
#include <hip/hip_bf16.h>
#include <math.h>

constexpr int kN = 10000;   // nodes
constexpr int kE = 160000;  // edges
constexpr float kSlope = 0.2f;

typedef short v8s __attribute__((ext_vector_type(8)));
typedef float f32x4 __attribute__((ext_vector_type(4)));
typedef unsigned short ushort_t;

__device__ __forceinline__ float lrelu(float x) { return x > 0.f ? x : kSlope * x; }
__device__ __forceinline__ float elu_f(float x) { return x > 0.f ? x : (__expf(x) - 1.f); }
__device__ __forceinline__ float b2f(ushort_t u) {
    return __uint_as_float(((unsigned)u) << 16);
}
__device__ __forceinline__ float bl(unsigned u) { return __uint_as_float(u << 16); }
__device__ __forceinline__ float bh(unsigned u) { return __uint_as_float(u & 0xffff0000u); }
__device__ __forceinline__ ushort_t f2b(float f) {   // RNE f32->bf16
    unsigned u = __float_as_uint(f);
    return (ushort_t)((u + 0x7FFFu + ((u >> 16) & 1u)) >> 16);
}

// ---------------- dtype detection + deg/cnt zeroing (one launch) ----------------
__global__ void detect_zero(const void* __restrict__ x, const void* __restrict__ dsti,
                            int* __restrict__ flags, int* __restrict__ deg) {
    if (blockIdx.x == 0) {
        __shared__ int sb[2];
        int tid = threadIdx.x;
        if (tid == 0) { sb[0] = 0; sb[1] = 0; }
        __syncthreads();
        const ushort_t* xb = (const ushort_t*)x;
        int big = 0;
        for (int i = tid; i < 4096; i += 256) {
            float v = b2f(xb[i]);
            if (!(fabsf(v) <= 1e4f)) big = 1;
        }
        const int* d32 = (const int*)dsti;
        int hi = 0;
        for (int i = tid; i < 4096; i += 256) hi |= d32[2 * i + 1];
        if (big) atomicOr(&sb[0], 1);
        if (hi)  atomicOr(&sb[1], 1);
        __syncthreads();
        if (tid == 0) { flags[0] = sb[0]; flags[1] = sb[1] ? 0 : 1; }
    } else {
        int i = (blockIdx.x - 1) * 256 + threadIdx.x;
        if (i < 2 * kN) deg[i] = 0;    // deg + cnt contiguous
    }
}

// ---------------- all flag-dependent prep in ONE launch (Xb segment removed) ------
struct PrepArgs {
    const void* sm[13];
    const void* W0; const void* W1; const void* W2; const void* Wm0; const void* Wm1;
    const void* srcIn; const void* dstIn;
    float* smallb;
    ushort_t* W0T; ushort_t* W1T; ushort_t* W2T; ushort_t* PQT; ushort_t* Wm1T;
    int* nsrc; int* ndst; int* deg;
    const int* flags;
};
// segments: 4865 | 131072 | 262144 | 262144 | 32768 | 8192 | 320000
constexpr int kPrepTotal = 4865 + 131072 + 262144 + 262144 + 32768 + 8192 + 320000;

__global__ void prep_all(PrepArgs a) {
    int i = blockIdx.x * 256 + threadIdx.x;
    if (i >= kPrepTotal) return;
    const int f32in = a.flags[0];
    auto cv = [&](const void* p, int idx) -> ushort_t {
        return f32in ? f2b(((const float*)p)[idx]) : ((const ushort_t*)p)[idx];
    };
    if (i < 4865) {   // small f32 tensors
        int seg, offi;
        if (i < 4608)      { seg = i >> 9; offi = i & 511; }
        else if (i < 4736) { seg = 9;  offi = i - 4608; }
        else if (i < 4800) { seg = 10; offi = i - 4736; }
        else if (i < 4864) { seg = 11; offi = i - 4800; }
        else               { seg = 12; offi = 0; }
        a.smallb[i] = f32in ? ((const float*)a.sm[seg])[offi]
                            : b2f(((const ushort_t*)a.sm[seg])[offi]);
        return;
    }
    i -= 4865;
    if (i < 131072) {   // W0T [512][256]
        int n = i >> 8, k = i & 255;
        a.W0T[i] = cv(a.W0, k * 512 + n);
        return;
    }
    i -= 131072;
    if (i < 262144) {   // W1T [512][512]
        int n = i >> 9, k = i & 511;
        a.W1T[i] = cv(a.W1, k * 512 + n);
        return;
    }
    i -= 262144;
    if (i < 262144) {   // W2T [512][512]
        int n = i >> 9, k = i & 511;
        a.W2T[i] = cv(a.W2, k * 512 + n);
        return;
    }
    i -= 262144;
    if (i < 32768) {    // PQT [256][128]
        int n = i >> 7, k = i & 127;
        a.PQT[i] = cv(a.Wm0, (k + ((n < 128) ? 0 : 128)) * 128 + (n & 127));
        return;
    }
    i -= 32768;
    if (i < 8192) {     // Wm1T [64][128]
        int n = i >> 7, k = i & 127;
        a.Wm1T[i] = cv(a.Wm1, k * 64 + n);
        return;
    }
    i -= 8192;
    {                   // index normalize + degree count
        const void* in = (i < kE) ? a.srcIn : a.dstIn;
        int j = (i < kE) ? i : i - kE;
        int v = a.flags[1] ? (int)((const long long*)in)[j] : ((const int*)in)[j];
        v = ((unsigned)v < (unsigned)kN) ? v : 0;
        if (i < kE) a.nsrc[j] = v;
        else { a.ndst[j] = v; atomicAdd(&a.deg[v], 1); }
    }
}

// ---------------- CSR build ----------------
__global__ __launch_bounds__(1024) void scan_off(const int* __restrict__ deg,
                                                 int* __restrict__ off, int n) {
    __shared__ int s[1024];
    int tid = threadIdx.x;
    int per = (n + 1023) >> 10;
    int base = tid * per;
    int sum = 0;
    for (int i = 0; i < per; ++i) { int j = base + i; if (j < n) sum += deg[j]; }
    s[tid] = sum;
    __syncthreads();
    for (int d = 1; d < 1024; d <<= 1) {
        int v = (tid >= d) ? s[tid - d] : 0;
        __syncthreads();
        s[tid] += v;
        __syncthreads();
    }
    int run = (tid > 0) ? s[tid - 1] : 0;
    for (int i = 0; i < per; ++i) {
        int j = base + i;
        if (j < n) { off[j] = run; run += deg[j]; }
    }
    if (tid == 0) off[n] = s[1023];
}

__global__ void fill_csr(const int* __restrict__ src, const int* __restrict__ dst,
                         const int* __restrict__ off, int* __restrict__ cnt,
                         int* __restrict__ ss, int* __restrict__ eid,
                         int* __restrict__ dpos, int n) {
    int i = blockIdx.x * 256 + threadIdx.x;
    if (i < n) {
        int d = dst[i];
        int pos = off[d] + atomicAdd(&cnt[d], 1);
        if (pos < kE) { ss[pos] = src[i]; eid[pos] = i; dpos[pos] = d; }
    }
}

// ---------------- LDS-staged MFMA GEMM (R0-proven K-chunk-32 structure) ----------------
// A [M,K] row-major: bf16, or f32 when (f32sel && gflags[0]) -> converted in-register
// during staging (bit-identical to the old prep-pass conversion).
// WT [N,K] bf16 row-major. C [M,N] bf16.
// ELER: N==512, blockIdx.x == head; fused el/er from f32 accumulators.
template <bool ELER>
__global__ __launch_bounds__(256) void gemm_mfma(const void* __restrict__ A,
                                                 const int* __restrict__ gflags,
                                                 int f32sel,
                                                 const ushort_t* __restrict__ WT,
                                                 ushort_t* __restrict__ Cout,
                                                 int M, int N, int K,
                                                 const float* __restrict__ al,
                                                 const float* __restrict__ ar,
                                                 float* __restrict__ el,
                                                 float* __restrict__ er) {
    __shared__ __align__(16) ushort_t As[4][64][8];
    __shared__ __align__(16) ushort_t Bs[4][128][8];
    __shared__ float elred[64][2][2];
    const int t = threadIdx.x;
    const int wave = t >> 6, lane = t & 63;
    const int l16 = lane & 15, q = lane >> 4;
    const int row0 = blockIdx.y * 64, col0 = blockIdx.x * 128;
    const int wm = (wave & 1) * 32, wn = (wave >> 1) * 64;
    const int am = t >> 2, ak8 = t & 3;
    const int sw = ak8 * 4;

    const int f32a = f32sel && gflags[0];
    const size_t arow = (size_t)min(row0 + am, M - 1) * K + ak8 * 8;
    const ushort_t* aB = (const ushort_t*)A + arow;
    const float*    aF = (const float*)A + arow;
    const ushort_t* bptr0 = WT + (size_t)(col0 + am) * K + ak8 * 8;
    const ushort_t* bptr1 = bptr0 + (size_t)64 * K;

    auto loadA = [&](int k0) -> uint4 {
        if (!f32a) return *(const uint4*)(aB + k0);
        float4 f0 = *(const float4*)(aF + k0);
        float4 f1 = *(const float4*)(aF + k0 + 4);
        uint4 r;
        r.x = (unsigned)f2b(f0.x) | ((unsigned)f2b(f0.y) << 16);
        r.y = (unsigned)f2b(f0.z) | ((unsigned)f2b(f0.w) << 16);
        r.z = (unsigned)f2b(f1.x) | ((unsigned)f2b(f1.y) << 16);
        r.w = (unsigned)f2b(f1.z) | ((unsigned)f2b(f1.w) << 16);
        return r;
    };

    uint4 ga  = loadA(0);
    uint4 gb0 = *(const uint4*)bptr0;
    uint4 gb1 = *(const uint4*)bptr1;

    f32x4 acc[2][4];
#pragma unroll
    for (int mt = 0; mt < 2; ++mt)
#pragma unroll
        for (int nt = 0; nt < 4; ++nt)
#pragma unroll
            for (int r = 0; r < 4; ++r) acc[mt][nt][r] = 0.f;

    for (int k0 = 0; k0 < K; k0 += 32) {
        __syncthreads();
        *(uint4*)&As[ak8][am ^ sw][0] = ga;
        *(uint4*)&Bs[ak8][am ^ sw][0] = gb0;
        *(uint4*)&Bs[ak8][(am + 64) ^ sw][0] = gb1;
        __syncthreads();
        if (k0 + 32 < K) {
            ga  = loadA(k0 + 32);
            gb0 = *(const uint4*)(bptr0 + k0 + 32);
            gb1 = *(const uint4*)(bptr1 + k0 + 32);
        }
        v8s af[2], bf[4];
        const int qs = q * 4;
#pragma unroll
        for (int mt = 0; mt < 2; ++mt)
            af[mt] = *(const v8s*)&As[q][(wm + mt * 16 + l16) ^ qs][0];
#pragma unroll
        for (int nt = 0; nt < 4; ++nt)
            bf[nt] = *(const v8s*)&Bs[q][(wn + nt * 16 + l16) ^ qs][0];
#pragma unroll
        for (int mt = 0; mt < 2; ++mt)
#pragma unroll
            for (int nt = 0; nt < 4; ++nt)
                acc[mt][nt] = __builtin_amdgcn_mfma_f32_16x16x32_bf16(af[mt], bf[nt],
                                                                      acc[mt][nt], 0, 0, 0);
    }
#pragma unroll
    for (int mt = 0; mt < 2; ++mt)
#pragma unroll
        for (int r = 0; r < 4; ++r) {
            int row = row0 + wm + mt * 16 + q * 4 + r;
            if (row < M) {
#pragma unroll
                for (int nt = 0; nt < 4; ++nt)
                    Cout[(size_t)row * N + col0 + wn + nt * 16 + l16] = f2b(acc[mt][nt][r]);
            }
        }
    if (ELER) {
        const int head = blockIdx.x;
        float alv[4], arv[4];
#pragma unroll
        for (int nt = 0; nt < 4; ++nt) {
            alv[nt] = al[head * 128 + wn + nt * 16 + l16];
            arv[nt] = ar[head * 128 + wn + nt * 16 + l16];
        }
#pragma unroll
        for (int mt = 0; mt < 2; ++mt)
#pragma unroll
            for (int r = 0; r < 4; ++r) {
                float pel = 0.f, per = 0.f;
#pragma unroll
                for (int nt = 0; nt < 4; ++nt) {
                    pel += acc[mt][nt][r] * alv[nt];
                    per += acc[mt][nt][r] * arv[nt];
                }
                pel += __shfl_xor(pel, 1); per += __shfl_xor(per, 1);
                pel += __shfl_xor(pel, 2); per += __shfl_xor(per, 2);
                pel += __shfl_xor(pel, 4); per += __shfl_xor(per, 4);
                pel += __shfl_xor(pel, 8); per += __shfl_xor(per, 8);
                if (l16 == 0) {
                    int rl = wm + mt * 16 + q * 4 + r;
                    elred[rl][wave >> 1][0] = pel;
                    elred[rl][wave >> 1][1] = per;
                }
            }
        __syncthreads();
        if (t < 64) {
            int row = row0 + t;
            if (row < M) {
                el[row * 4 + head] = elred[t][0][0] + elred[t][1][0];
                er[row * 4 + head] = elred[t][0][1] + elred[t][1][1];
            }
        }
    }
}

// ---------------- GAT softmax + aggregation: 3-slot / 12-edge-deep pipeline ----------------
// softmax = (sum e*f)/(sum e); feat bf16; resid bf16 (may alias hl).
// EPI 1: write bf16 [node][512]; EPI 2: write head-mean bf16 [node][128].
template <bool RES, bool ACT, int EPI>
__global__ __launch_bounds__(256) void gat_agg(const ushort_t* __restrict__ feat,
                                               const float* __restrict__ el,
                                               const float* __restrict__ er,
                                               const int* __restrict__ off,
                                               const int* __restrict__ ss,
                                               const ushort_t* residb,
                                               const float* __restrict__ bias,
                                               ushort_t* hl) {
    const int node = blockIdx.x * 4 + (threadIdx.x >> 6);
    const int lane = threadIdx.x & 63;
    if (node >= kN) return;
    const int off0 = off[node];
    const int deg = off[node + 1] - off0;
    float4 er4 = *(const float4*)(er + node * 4);
    const int head = lane >> 4;
    const float erh = (head == 0) ? er4.x : (head == 1) ? er4.y : (head == 2) ? er4.z : er4.w;
    const int c0 = lane * 8;
    const ushort_t* fbase = feat + c0;

    float den = 0.f;
    float acc[8] = {};
    if (deg > 0) {
        float e0[4], e1[4], e2[4];
        uint4 f0[4], f1[4], f2[4];
        auto LD = [&](int bj, float* ev, uint4* fv) {
#pragma unroll
            for (int i = 0; i < 4; ++i) {
                int s = ss[off0 + min(bj + i, deg - 1)];
                ev[i] = el[s * 4 + head];
                fv[i] = *(const uint4*)(fbase + (size_t)s * 512);
            }
        };
        auto CONS = [&](int bj, const float* ev, const uint4* fv) {
#pragma unroll
            for (int i = 0; i < 4; ++i) {
                if (bj + i < deg) {
                    float w = __expf(lrelu(ev[i] + erh));
                    den += w;
                    acc[0] += w * bl(fv[i].x); acc[1] += w * bh(fv[i].x);
                    acc[2] += w * bl(fv[i].y); acc[3] += w * bh(fv[i].y);
                    acc[4] += w * bl(fv[i].z); acc[5] += w * bh(fv[i].z);
                    acc[6] += w * bl(fv[i].w); acc[7] += w * bh(fv[i].w);
                }
            }
        };
        LD(0, e0, f0);
        LD(4, e1, f1);
        LD(8, e2, f2);
        for (int j = 0; j < deg; j += 12) {
            CONS(j, e0, f0);
            if (j + 12 < deg) LD(j + 12, e0, f0);
            CONS(j + 4, e1, f1);
            if (j + 16 < deg) LD(j + 16, e1, f1);
            CONS(j + 8, e2, f2);
            if (j + 20 < deg) LD(j + 20, e2, f2);
        }
    }
    const float inv = 1.f / fmaxf(den, 1e-9f);
    float4 b0 = *(const float4*)(bias + c0);
    float4 b1 = *(const float4*)(bias + c0 + 4);
    float v[8];
#pragma unroll
    for (int r = 0; r < 8; ++r) v[r] = acc[r] * inv;
    v[0] += b0.x; v[1] += b0.y; v[2] += b0.z; v[3] += b0.w;
    v[4] += b1.x; v[5] += b1.y; v[6] += b1.z; v[7] += b1.w;
    if (RES) {
        uint4 rv = *(const uint4*)(residb + (size_t)node * 512 + c0);
        v[0] += bl(rv.x); v[1] += bh(rv.x);
        v[2] += bl(rv.y); v[3] += bh(rv.y);
        v[4] += bl(rv.z); v[5] += bh(rv.z);
        v[6] += bl(rv.w); v[7] += bh(rv.w);
    }
    if (ACT) {
#pragma unroll
        for (int r = 0; r < 8; ++r) v[r] = elu_f(v[r]);
    }
    if (EPI == 1) {
        ushort_t* hp = hl + (size_t)node * 512 + c0;
        ushort4 h0 = {f2b(v[0]), f2b(v[1]), f2b(v[2]), f2b(v[3])};
        ushort4 h1 = {f2b(v[4]), f2b(v[5]), f2b(v[6]), f2b(v[7])};
        *(ushort4*)hp = h0;
        *(ushort4*)(hp + 4) = h1;
    }
    if (EPI == 2) {
        float m[8];
#pragma unroll
        for (int r = 0; r < 8; ++r) {
            float x = v[r] + __shfl_xor(v[r], 16);
            x += __shfl_xor(x, 32);
            m[r] = 0.25f * x;
        }
        if (lane < 16) {
            ushort_t* hp = hl + (size_t)node * 128 + lane * 8;
            ushort4 h0 = {f2b(m[0]), f2b(m[1]), f2b(m[2]), f2b(m[3])};
            ushort4 h1 = {f2b(m[4]), f2b(m[5]), f2b(m[6]), f2b(m[7])};
            *(ushort4*)hp = h0;
            *(ushort4*)(hp + 4) = h1;
        }
    }
}

// ---------------- MFMA edge MLP: LDS-free direct-fragment gather ----------------
__global__ __launch_bounds__(256) void edge_mfma(const ushort_t* __restrict__ PQb,
                                                 const float* __restrict__ bm0f,
                                                 const ushort_t* __restrict__ Wm1T,
                                                 const float* __restrict__ bm1f,
                                                 const float* __restrict__ wm2f,
                                                 const float* __restrict__ bm2f,
                                                 const int* __restrict__ ss,
                                                 const int* __restrict__ dpos,
                                                 const int* __restrict__ eid,
                                                 void* __restrict__ outv,
                                                 const int* __restrict__ flags) {
    const int t = threadIdx.x;
    const int wave = t >> 6, lane = t & 63;
    const int l16 = lane & 15, q = lane >> 4;
    const int base = blockIdx.x * 64 + wave * 16;
    const int pos = base + l16;
    const int s = ss[pos], d = dpos[pos];
    const ushort_t* prow = PQb + (size_t)s * 256;
    const ushort_t* qrow = PQb + (size_t)d * 256 + 128;

    f32x4 acc[4];
#pragma unroll
    for (int nt = 0; nt < 4; ++nt)
#pragma unroll
        for (int r = 0; r < 4; ++r) acc[nt][r] = 0.f;

#pragma unroll
    for (int ks = 0; ks < 4; ++ks) {
        const int k0 = ks * 32 + q * 8;
        uint4 pv = *(const uint4*)(prow + k0);
        uint4 qv = *(const uint4*)(qrow + k0);
        float4 bb0 = *(const float4*)(bm0f + k0);
        float4 bb1 = *(const float4*)(bm0f + k0 + 4);
        v8s a;
        a[0] = (short)f2b(fmaxf(bl(pv.x) + bl(qv.x) + bb0.x, 0.f));
        a[1] = (short)f2b(fmaxf(bh(pv.x) + bh(qv.x) + bb0.y, 0.f));
        a[2] = (short)f2b(fmaxf(bl(pv.y) + bl(qv.y) + bb0.z, 0.f));
        a[3] = (short)f2b(fmaxf(bh(pv.y) + bh(qv.y) + bb0.w, 0.f));
        a[4] = (short)f2b(fmaxf(bl(pv.z) + bl(qv.z) + bb1.x, 0.f));
        a[5] = (short)f2b(fmaxf(bh(pv.z) + bh(qv.z) + bb1.y, 0.f));
        a[6] = (short)f2b(fmaxf(bl(pv.w) + bl(qv.w) + bb1.z, 0.f));
        a[7] = (short)f2b(fmaxf(bh(pv.w) + bh(qv.w) + bb1.w, 0.f));
#pragma unroll
        for (int nt = 0; nt < 4; ++nt) {
            v8s b = *(const v8s*)(Wm1T + (size_t)(nt * 16 + l16) * 128 + k0);
            acc[nt] = __builtin_amdgcn_mfma_f32_16x16x32_bf16(a, b, acc[nt], 0, 0, 0);
        }
    }
    float b1v[4], w2v[4];
#pragma unroll
    for (int nt = 0; nt < 4; ++nt) {
        b1v[nt] = bm1f[nt * 16 + l16];
        w2v[nt] = wm2f[nt * 16 + l16];
    }
    float b2 = bm2f[0];
    const int f32out = flags[0];
#pragma unroll
    for (int r = 0; r < 4; ++r) {
        float v = 0.f;
#pragma unroll
        for (int nt = 0; nt < 4; ++nt)
            v += fmaxf(acc[nt][r] + b1v[nt], 0.f) * w2v[nt];
        v += __shfl_xor(v, 1);
        v += __shfl_xor(v, 2);
        v += __shfl_xor(v, 4);
        v += __shfl_xor(v, 8);
        if (l16 == 0) {
            int e = eid[base + q * 4 + r];
            float rr = 1.f / (1.f + __expf(-(v + b2)));
            if (f32out) ((float*)outv)[e] = rr;
            else        ((ushort_t*)outv)[e] = f2b(rr);
        }
    }
}

// ---------------- host launch ----------------
extern "C" void kernel_launch(void* const* d_in, const int* in_sizes, int n_in,
                              void* d_out, int out_size, void* d_ws, size_t ws_size,
                              hipStream_t stream) {
    (void)in_sizes; (void)n_in; (void)out_size; (void)ws_size;

    float* w = (float*)d_ws;
    size_t o = 0;
    auto alloc = [&](size_t n) { float* p = w + o; o += (n + 3) & ~size_t(3); return p; };
    float* smallb = alloc(4868);
    float* al0f = smallb + 0;    float* ar0f = smallb + 512;  float* b0f  = smallb + 1024;
    float* al1f = smallb + 1536; float* ar1f = smallb + 2048; float* b1f  = smallb + 2560;
    float* al2f = smallb + 3072; float* ar2f = smallb + 3584; float* b2f_ = smallb + 4096;
    float* bm0f = smallb + 4608; float* bm1f = smallb + 4736;
    float* wm2f = smallb + 4800; float* bm2f = smallb + 4864;
    float* elb  = alloc((size_t)kN * 4);
    float* erb  = alloc((size_t)kN * 4);
    ushort_t* Fb  = (ushort_t*)alloc((size_t)kN * 256);      // bf16 feat [10000][512]
    ushort_t* AHL = (ushort_t*)alloc((size_t)kN * 256);      // bf16 layer act [10000][512]
    ushort_t* MHb = (ushort_t*)alloc((size_t)kN * 64);       // bf16 head-mean [10000][128]
    ushort_t* W0T  = (ushort_t*)alloc(65536);                // [512][256]
    ushort_t* W1T  = (ushort_t*)alloc(131072);               // [512][512]
    ushort_t* W2T  = (ushort_t*)alloc(131072);               // [512][512]
    ushort_t* PQT  = (ushort_t*)alloc(16384);                // [256][128]
    ushort_t* Wm1T = (ushort_t*)alloc(4096);                 // [64][128]
    int* ip    = (int*)(w + o);
    int* flags = ip;
    int* deg   = ip + 4;
    int* cnt   = deg + kN;
    int* off   = cnt + kN;
    int* ss    = off + 10004;
    int* eid   = ss + kE;
    int* dpos  = eid + kE;
    int* nsrc  = dpos + kE;
    int* ndst  = nsrc + kE;

    ushort_t* PQb = Fb;   // bf16 [10000][256] P|Q; written after L2 agg frees Fb

    dim3 blk(256);

    // 0) flags + deg/cnt zero
    detect_zero<<<dim3(1 + (2 * kN + 255) / 256), blk, 0, stream>>>(d_in[0], d_in[2], flags, deg);

    // 1) all flag-dependent prep + index normalize + degree count (no Xb pass)
    PrepArgs a;
    const int sidx[13] = {4, 5, 6, 8, 9, 10, 12, 13, 14, 16, 18, 19, 20};
    for (int i = 0; i < 13; ++i) a.sm[i] = d_in[sidx[i]];
    a.W0 = d_in[3]; a.W1 = d_in[7]; a.W2 = d_in[11]; a.Wm0 = d_in[15]; a.Wm1 = d_in[17];
    a.srcIn = d_in[1]; a.dstIn = d_in[2];
    a.smallb = smallb; a.W0T = W0T; a.W1T = W1T; a.W2T = W2T; a.PQT = PQT; a.Wm1T = Wm1T;
    a.nsrc = nsrc; a.ndst = ndst; a.deg = deg; a.flags = flags;
    prep_all<<<dim3((kPrepTotal + 255) / 256), blk, 0, stream>>>(a);

    // 2) CSR scan + fill
    scan_off<<<dim3(1), dim3(1024), 0, stream>>>(deg, off, kN);
    fill_csr<<<dim3((kE + 255) / 256), blk, 0, stream>>>(nsrc, ndst, off, cnt, ss, eid, dpos, kE);

    const int gy = (kN + 63) / 64;      // 157 row tiles
    const int ga = (kN + 3) / 4;        // 2500 agg blocks

    // 3) Layer 0: Fb = x @ W0 (+ fused el/er); A = d_in[0], f32->bf16 in staging
    gemm_mfma<true><<<dim3(4, gy), blk, 0, stream>>>(d_in[0], flags, 1, W0T, Fb,
                                                     kN, 512, 256, al0f, ar0f, elb, erb);
    gat_agg<false, true, 1><<<dim3(ga), blk, 0, stream>>>(Fb, elb, erb, off, ss,
                                                          nullptr, b0f, AHL);

    // 4) Layer 1 (residual, ELU): AHL @ W1, K=512; in-place bf16 resid+out
    gemm_mfma<true><<<dim3(4, gy), blk, 0, stream>>>(AHL, flags, 0, W1T, Fb,
                                                     kN, 512, 512, al1f, ar1f, elb, erb);
    gat_agg<true, true, 1><<<dim3(ga), blk, 0, stream>>>(Fb, elb, erb, off, ss,
                                                         AHL, b1f, AHL);

    // 5) Layer 2 (residual, no act) + fused head-mean bf16
    gemm_mfma<true><<<dim3(4, gy), blk, 0, stream>>>(AHL, flags, 0, W2T, Fb,
                                                     kN, 512, 512, al2f, ar2f, elb, erb);
    gat_agg<true, false, 2><<<dim3(ga), blk, 0, stream>>>(Fb, elb, erb, off, ss,
                                                          AHL, b2f_, MHb);

    // 6) PQb (bf16) = head-mean @ [Wm0_top | Wm0_bot], K=128  (PQb overlays Fb)
    gemm_mfma<false><<<dim3(2, gy), blk, 0, stream>>>(MHb, flags, 0, PQT, PQb,
                                                      kN, 256, 128,
                                                      nullptr, nullptr, nullptr, nullptr);

    // 7) LDS-free edge MLP + sigmoid
    edge_mfma<<<dim3(kE / 64), blk, 0, stream>>>(PQb, bm0f, Wm1T, bm1f, wm2f, bm2f,
                                                 ss, dpos, eid, d_out, flags);
}